// Round 2
// baseline (127.737 us; speedup 1.0000x reference)
//
#include <hip/hip_runtime.h>
#include <hip/hip_bf16.h>

// Sparse4DHead1st deformable aggregation + output_proj + concat.
// Inputs (fp32): fm0..fm3, points_2d, weights, instance_feature, w_proj, b_proj
// Output (fp32): [1, 900, 512] = concat(acc @ w_proj + b, instance_feature)

#define A_TOT 900
#define P_PTS 13
#define N_CAM 6
#define C_CH  256
#define N_GRP 8
#define N_LVL 4

__global__ __launch_bounds__(256) void daf_fused_kernel(
    const float* __restrict__ fm0, const float* __restrict__ fm1,
    const float* __restrict__ fm2, const float* __restrict__ fm3,
    const float* __restrict__ pts, const float* __restrict__ wts,
    const float* __restrict__ inst, const float* __restrict__ wproj,
    const float* __restrict__ bproj, float* __restrict__ out)
{
    const int a    = blockIdx.x;        // anchor, 0..899
    const int tid  = threadIdx.x;       // 0..255
    const int wave = tid >> 6;          // wave id == feature level
    const int lane = tid & 63;

    // per-wave (per-level) constants
    const float* fm; int H, W;
    if (wave == 0)      { fm = fm0; H = 64; W = 176; }
    else if (wave == 1) { fm = fm1; H = 32; W = 88;  }
    else if (wave == 2) { fm = fm2; H = 16; W = 44;  }
    else                { fm = fm3; H = 8;  W = 22;  }
    const float fW = (float)W, fH = (float)H;
    const int HW = H * W;

    const int c0 = lane << 2;          // channel base (4 channels per lane)
    const int g  = lane >> 3;          // group index = c0 / 32

    const float2* __restrict__ pts_a = (const float2*)(pts + (size_t)a * (P_PTS * N_CAM * 2));
    const float*  __restrict__ wts_a = wts + (size_t)a * (P_PTS * N_CAM * N_LVL * N_GRP);

    float4 acc = make_float4(0.f, 0.f, 0.f, 0.f);

    for (int p = 0; p < P_PTS; ++p) {
#pragma unroll 2
        for (int cam = 0; cam < N_CAM; ++cam) {
            const int pc = p * N_CAM + cam;
            float2 pt = pts_a[pc];
            float x = pt.x * fW - 0.5f;
            float y = pt.y * fH - 0.5f;
            float x0f = floorf(x), y0f = floorf(y);
            int   x0 = (int)x0f,  y0 = (int)y0f;
            float wx1 = x - x0f,  wy1 = y - y0f;
            float wx0 = 1.f - wx1, wy0 = 1.f - wy1;
            // zero-padding semantics: invalid coordinate zeroes its corners
            if (x0 < 0 || x0 >= W)         wx0 = 0.f;
            if (x0 + 1 < 0 || x0 + 1 >= W) wx1 = 0.f;
            if (y0 < 0 || y0 >= H)         wy0 = 0.f;
            if (y0 + 1 < 0 || y0 + 1 >= H) wy1 = 0.f;

            float w = wts_a[pc * (N_LVL * N_GRP) + wave * N_GRP + g];
            wx0 *= w; wx1 *= w;

            int xc0 = min(max(x0, 0), W - 1);
            int xc1 = min(max(x0 + 1, 0), W - 1);
            int yc0 = min(max(y0, 0), H - 1);
            int yc1 = min(max(y0 + 1, 0), H - 1);

            const int base = cam * HW;
            const int r0 = base + yc0 * W;
            const int r1 = base + yc1 * W;

            float4 v00 = *(const float4*)(fm + (size_t)(r0 + xc0) * C_CH + c0);
            float4 v10 = *(const float4*)(fm + (size_t)(r0 + xc1) * C_CH + c0);
            float4 v01 = *(const float4*)(fm + (size_t)(r1 + xc0) * C_CH + c0);
            float4 v11 = *(const float4*)(fm + (size_t)(r1 + xc1) * C_CH + c0);

            float w00 = wx0 * wy0, w10 = wx1 * wy0;
            float w01 = wx0 * wy1, w11 = wx1 * wy1;

            acc.x = fmaf(v00.x, w00, acc.x);
            acc.y = fmaf(v00.y, w00, acc.y);
            acc.z = fmaf(v00.z, w00, acc.z);
            acc.w = fmaf(v00.w, w00, acc.w);
            acc.x = fmaf(v10.x, w10, acc.x);
            acc.y = fmaf(v10.y, w10, acc.y);
            acc.z = fmaf(v10.z, w10, acc.z);
            acc.w = fmaf(v10.w, w10, acc.w);
            acc.x = fmaf(v01.x, w01, acc.x);
            acc.y = fmaf(v01.y, w01, acc.y);
            acc.z = fmaf(v01.z, w01, acc.z);
            acc.w = fmaf(v01.w, w01, acc.w);
            acc.x = fmaf(v11.x, w11, acc.x);
            acc.y = fmaf(v11.y, w11, acc.y);
            acc.z = fmaf(v11.z, w11, acc.z);
            acc.w = fmaf(v11.w, w11, acc.w);
        }
    }

    // reduce partial sums across the 4 level-waves
    __shared__ float s_part[4][C_CH];
    __shared__ float s_tot[C_CH];
    *(float4*)&s_part[wave][c0] = acc;
    __syncthreads();
    s_tot[tid] = s_part[0][tid] + s_part[1][tid] + s_part[2][tid] + s_part[3][tid];
    __syncthreads();

    // fused projection: out[a, tid] = sum_k s_tot[k] * wproj[k, tid] + b[tid]
    float r0s = 0.f, r1s = 0.f, r2s = 0.f, r3s = 0.f;
#pragma unroll 4
    for (int k = 0; k < C_CH; k += 4) {
        r0s = fmaf(s_tot[k + 0], wproj[(size_t)(k + 0) * C_CH + tid], r0s);
        r1s = fmaf(s_tot[k + 1], wproj[(size_t)(k + 1) * C_CH + tid], r1s);
        r2s = fmaf(s_tot[k + 2], wproj[(size_t)(k + 2) * C_CH + tid], r2s);
        r3s = fmaf(s_tot[k + 3], wproj[(size_t)(k + 3) * C_CH + tid], r3s);
    }
    float r = (r0s + r1s) + (r2s + r3s) + bproj[tid];

    out[(size_t)a * 512 + tid]       = r;
    out[(size_t)a * 512 + 256 + tid] = inst[(size_t)a * C_CH + tid];
}

extern "C" void kernel_launch(void* const* d_in, const int* in_sizes, int n_in,
                              void* d_out, int out_size, void* d_ws, size_t ws_size,
                              hipStream_t stream) {
    const float* fm0   = (const float*)d_in[0];
    const float* fm1   = (const float*)d_in[1];
    const float* fm2   = (const float*)d_in[2];
    const float* fm3   = (const float*)d_in[3];
    const float* pts   = (const float*)d_in[4];
    const float* wts   = (const float*)d_in[5];
    const float* inst  = (const float*)d_in[6];
    const float* wproj = (const float*)d_in[7];
    const float* bproj = (const float*)d_in[8];
    float* out = (float*)d_out;

    daf_fused_kernel<<<A_TOT, 256, 0, stream>>>(
        fm0, fm1, fm2, fm3, pts, wts, inst, wproj, bproj, out);
}

// Round 3
// 125.701 us; speedup vs baseline: 1.0162x; 1.0162x over previous
//
#include <hip/hip_runtime.h>
#include <hip/hip_bf16.h>

// Sparse4DHead1st deformable aggregation + output_proj + concat.
// Inputs (fp32): fm0..fm3, points_2d, weights, instance_feature, w_proj, b_proj
// Output (fp32): [1, 900, 512] = concat(acc @ w_proj + b, instance_feature)
//
// Round 2: latency-bound fix. 1024-thread blocks (16 waves):
//   wave = (chunk 0..3) x (level 0..3); each wave gathers ~20 of 78 (p,cam)
//   samples for its level. 2 blocks/CU resident -> ~32 waves/CU (vs 11).

#define A_TOT 900
#define P_PTS 13
#define N_CAM 6
#define C_CH  256
#define N_GRP 8
#define N_LVL 4
#define N_PC  (P_PTS * N_CAM)   // 78

__global__ __launch_bounds__(1024, 8) void daf_fused_kernel(
    const float* __restrict__ fm0, const float* __restrict__ fm1,
    const float* __restrict__ fm2, const float* __restrict__ fm3,
    const float* __restrict__ pts, const float* __restrict__ wts,
    const float* __restrict__ inst, const float* __restrict__ wproj,
    const float* __restrict__ bproj, float* __restrict__ out)
{
    const int a    = blockIdx.x;        // anchor, 0..899
    const int tid  = threadIdx.x;       // 0..1023
    const int wv   = tid >> 6;          // 0..15
    const int lane = tid & 63;
    const int level = wv & 3;
    const int chunk = wv >> 2;          // 0..3

    // per-level constants
    const float* fm; int H, W;
    if (level == 0)      { fm = fm0; H = 64; W = 176; }
    else if (level == 1) { fm = fm1; H = 32; W = 88;  }
    else if (level == 2) { fm = fm2; H = 16; W = 44;  }
    else                 { fm = fm3; H = 8;  W = 22;  }
    const float fW = (float)W, fH = (float)H;
    const int HW = H * W;

    const int c0 = lane << 2;          // channel base (4 channels per lane)
    const int g  = lane >> 3;          // group index = c0 / 32

    const float2* __restrict__ pts_a = (const float2*)(pts + (size_t)a * (N_PC * 2));
    const float*  __restrict__ wts_a = wts + (size_t)a * (N_PC * N_LVL * N_GRP);

    const int start = chunk * 20;
    const int end   = (chunk == 3) ? N_PC : (start + 20);

    float4 acc = make_float4(0.f, 0.f, 0.f, 0.f);

#pragma unroll 2
    for (int pc = start; pc < end; ++pc) {
        const int cam = pc % N_CAM;
        float2 pt = pts_a[pc];
        float x = pt.x * fW - 0.5f;
        float y = pt.y * fH - 0.5f;
        float x0f = floorf(x), y0f = floorf(y);
        int   x0 = (int)x0f,  y0 = (int)y0f;
        float wx1 = x - x0f,  wy1 = y - y0f;
        float wx0 = 1.f - wx1, wy0 = 1.f - wy1;
        // zero-padding semantics: invalid coordinate zeroes its corners
        if (x0 < 0 || x0 >= W)         wx0 = 0.f;
        if (x0 + 1 < 0 || x0 + 1 >= W) wx1 = 0.f;
        if (y0 < 0 || y0 >= H)         wy0 = 0.f;
        if (y0 + 1 < 0 || y0 + 1 >= H) wy1 = 0.f;

        float w = wts_a[pc * (N_LVL * N_GRP) + level * N_GRP + g];
        wx0 *= w; wx1 *= w;

        int xc0 = min(max(x0, 0), W - 1);
        int xc1 = min(max(x0 + 1, 0), W - 1);
        int yc0 = min(max(y0, 0), H - 1);
        int yc1 = min(max(y0 + 1, 0), H - 1);

        const int base = cam * HW;
        const int r0 = base + yc0 * W;
        const int r1 = base + yc1 * W;

        float4 v00 = *(const float4*)(fm + (size_t)(r0 + xc0) * C_CH + c0);
        float4 v10 = *(const float4*)(fm + (size_t)(r0 + xc1) * C_CH + c0);
        float4 v01 = *(const float4*)(fm + (size_t)(r1 + xc0) * C_CH + c0);
        float4 v11 = *(const float4*)(fm + (size_t)(r1 + xc1) * C_CH + c0);

        float w00 = wx0 * wy0, w10 = wx1 * wy0;
        float w01 = wx0 * wy1, w11 = wx1 * wy1;

        acc.x = fmaf(v00.x, w00, acc.x);
        acc.y = fmaf(v00.y, w00, acc.y);
        acc.z = fmaf(v00.z, w00, acc.z);
        acc.w = fmaf(v00.w, w00, acc.w);
        acc.x = fmaf(v10.x, w10, acc.x);
        acc.y = fmaf(v10.y, w10, acc.y);
        acc.z = fmaf(v10.z, w10, acc.z);
        acc.w = fmaf(v10.w, w10, acc.w);
        acc.x = fmaf(v01.x, w01, acc.x);
        acc.y = fmaf(v01.y, w01, acc.y);
        acc.z = fmaf(v01.z, w01, acc.z);
        acc.w = fmaf(v01.w, w01, acc.w);
        acc.x = fmaf(v11.x, w11, acc.x);
        acc.y = fmaf(v11.y, w11, acc.y);
        acc.z = fmaf(v11.z, w11, acc.z);
        acc.w = fmaf(v11.w, w11, acc.w);
    }

    // reduce partial sums across the 16 waves
    __shared__ float s_part[16][C_CH];
    __shared__ float s_tot[C_CH];
    __shared__ float s_proj[4][C_CH];

    *(float4*)&s_part[wv][c0] = acc;
    __syncthreads();

    if (tid < C_CH) {
        float t = 0.f;
#pragma unroll
        for (int i = 0; i < 16; ++i) t += s_part[i][tid];
        s_tot[tid] = t;
    }
    __syncthreads();

    // fused projection, 4-way split over k:
    // thread t: j = t & 255, q = t >> 8 sums k in [q*64, q*64+64)
    {
        const int j = tid & (C_CH - 1);
        const int q = tid >> 8;
        const int kb = q * 64;
        float r0s = 0.f, r1s = 0.f, r2s = 0.f, r3s = 0.f;
#pragma unroll 4
        for (int k = kb; k < kb + 64; k += 4) {
            r0s = fmaf(s_tot[k + 0], wproj[(size_t)(k + 0) * C_CH + j], r0s);
            r1s = fmaf(s_tot[k + 1], wproj[(size_t)(k + 1) * C_CH + j], r1s);
            r2s = fmaf(s_tot[k + 2], wproj[(size_t)(k + 2) * C_CH + j], r2s);
            r3s = fmaf(s_tot[k + 3], wproj[(size_t)(k + 3) * C_CH + j], r3s);
        }
        s_proj[q][j] = (r0s + r1s) + (r2s + r3s);
    }
    __syncthreads();

    if (tid < C_CH) {
        float r = (s_proj[0][tid] + s_proj[1][tid]) + (s_proj[2][tid] + s_proj[3][tid])
                  + bproj[tid];
        out[(size_t)a * 512 + tid] = r;
    } else if (tid < 2 * C_CH) {
        const int j = tid - C_CH;
        out[(size_t)a * 512 + C_CH + j] = inst[(size_t)a * C_CH + j];
    }
}

extern "C" void kernel_launch(void* const* d_in, const int* in_sizes, int n_in,
                              void* d_out, int out_size, void* d_ws, size_t ws_size,
                              hipStream_t stream) {
    const float* fm0   = (const float*)d_in[0];
    const float* fm1   = (const float*)d_in[1];
    const float* fm2   = (const float*)d_in[2];
    const float* fm3   = (const float*)d_in[3];
    const float* pts   = (const float*)d_in[4];
    const float* wts   = (const float*)d_in[5];
    const float* inst  = (const float*)d_in[6];
    const float* wproj = (const float*)d_in[7];
    const float* bproj = (const float*)d_in[8];
    float* out = (float*)d_out;

    daf_fused_kernel<<<A_TOT, 1024, 0, stream>>>(
        fm0, fm1, fm2, fm3, pts, wts, inst, wproj, bproj, out);
}

// Round 4
// 90.455 us; speedup vs baseline: 1.4122x; 1.3897x over previous
//
#include <hip/hip_runtime.h>
#include <hip/hip_bf16.h>

// Sparse4DHead1st deformable aggregation + output_proj + concat.
// Inputs (fp32): fm0..fm3, points_2d, weights, instance_feature, w_proj, b_proj
// Output (fp32): [1, 900, 512] = concat(acc @ w_proj + b, instance_feature)
//
// Round 4: traffic-bound fix. Prepass converts fm0..fm3 fp32->bf16 into d_ws
// (halves gather miss traffic, the measured 3.4 TB/s wall); gather kernel
// reads bf16. Falls back to fp32 gather if ws_size is too small.

#define A_TOT 900
#define P_PTS 13
#define N_CAM 6
#define C_CH  256
#define N_GRP 8
#define N_LVL 4
#define N_PC  (P_PTS * N_CAM)   // 78

// bf16 fm segment sizes (elements)
#define S0 17301504   // 6*64*176*256
#define S1 4325376    // 6*32*88*256
#define S2 1081344    // 6*16*44*256
#define S3 270336     // 6*8*22*256
#define S_TOT (S0 + S1 + S2 + S3)          // 22,978,560 elts
#define WS_NEEDED ((size_t)S_TOT * 2)      // 45,957,120 bytes

__device__ __forceinline__ float bf2f(unsigned short u) {
    unsigned int t = ((unsigned int)u) << 16;
    float f;
    __builtin_memcpy(&f, &t, 4);
    return f;
}

__device__ __forceinline__ unsigned short f2b(float x) {
    __hip_bfloat16 h = __float2bfloat16(x);   // RNE
    unsigned short b;
    __builtin_memcpy(&b, &h, 2);
    return b;
}

// ---------------- prepass: fp32 -> bf16 ----------------
__global__ __launch_bounds__(256) void convert_bf16_kernel(
    const float* __restrict__ f0, const float* __restrict__ f1,
    const float* __restrict__ f2, const float* __restrict__ f3,
    unsigned short* __restrict__ out)
{
    const size_t n8 = S_TOT / 8;
    for (size_t i = (size_t)blockIdx.x * blockDim.x + threadIdx.x; i < n8;
         i += (size_t)gridDim.x * blockDim.x) {
        size_t base = i * 8;
        const float* src;
        if (base < S0)                src = f0 + base;
        else if (base < S0 + S1)      src = f1 + (base - S0);
        else if (base < S0 + S1 + S2) src = f2 + (base - S0 - S1);
        else                          src = f3 + (base - S0 - S1 - S2);

        float4 a = *(const float4*)(src);
        float4 b = *(const float4*)(src + 4);
        uint4 o;
        o.x = (unsigned int)f2b(a.x) | ((unsigned int)f2b(a.y) << 16);
        o.y = (unsigned int)f2b(a.z) | ((unsigned int)f2b(a.w) << 16);
        o.z = (unsigned int)f2b(b.x) | ((unsigned int)f2b(b.y) << 16);
        o.w = (unsigned int)f2b(b.z) | ((unsigned int)f2b(b.w) << 16);
        *(uint4*)(out + base) = o;
    }
}

// ---------------- main fused kernel (bf16 gather) ----------------
__global__ __launch_bounds__(1024, 8) void daf_fused_bf16(
    const unsigned short* __restrict__ fmw,
    const float* __restrict__ pts, const float* __restrict__ wts,
    const float* __restrict__ inst, const float* __restrict__ wproj,
    const float* __restrict__ bproj, float* __restrict__ out)
{
    const int a    = blockIdx.x;
    const int tid  = threadIdx.x;
    const int wv   = tid >> 6;          // 0..15
    const int lane = tid & 63;
    const int level = wv & 3;
    const int chunk = wv >> 2;          // 0..3

    const unsigned short* fm; int H, W;
    if (level == 0)      { fm = fmw;                 H = 64; W = 176; }
    else if (level == 1) { fm = fmw + S0;            H = 32; W = 88;  }
    else if (level == 2) { fm = fmw + S0 + S1;       H = 16; W = 44;  }
    else                 { fm = fmw + S0 + S1 + S2;  H = 8;  W = 22;  }
    const float fW = (float)W, fH = (float)H;
    const int HW = H * W;

    const int c0 = lane << 2;          // 4 channels per lane
    const int g  = lane >> 3;

    const float2* __restrict__ pts_a = (const float2*)(pts + (size_t)a * (N_PC * 2));
    const float*  __restrict__ wts_a = wts + (size_t)a * (N_PC * N_LVL * N_GRP);

    const int start = chunk * 20;
    const int end   = (chunk == 3) ? N_PC : (start + 20);

    float4 acc = make_float4(0.f, 0.f, 0.f, 0.f);

#pragma unroll 2
    for (int pc = start; pc < end; ++pc) {
        const int cam = pc % N_CAM;
        float2 pt = pts_a[pc];
        float x = pt.x * fW - 0.5f;
        float y = pt.y * fH - 0.5f;
        float x0f = floorf(x), y0f = floorf(y);
        int   x0 = (int)x0f,  y0 = (int)y0f;
        float wx1 = x - x0f,  wy1 = y - y0f;
        float wx0 = 1.f - wx1, wy0 = 1.f - wy1;
        if (x0 < 0 || x0 >= W)         wx0 = 0.f;
        if (x0 + 1 < 0 || x0 + 1 >= W) wx1 = 0.f;
        if (y0 < 0 || y0 >= H)         wy0 = 0.f;
        if (y0 + 1 < 0 || y0 + 1 >= H) wy1 = 0.f;

        float w = wts_a[pc * (N_LVL * N_GRP) + level * N_GRP + g];
        wx0 *= w; wx1 *= w;

        int xc0 = min(max(x0, 0), W - 1);
        int xc1 = min(max(x0 + 1, 0), W - 1);
        int yc0 = min(max(y0, 0), H - 1);
        int yc1 = min(max(y0 + 1, 0), H - 1);

        const int base = cam * HW;
        const int r0 = base + yc0 * W;
        const int r1 = base + yc1 * W;

        ushort4 u00 = *(const ushort4*)(fm + (size_t)(r0 + xc0) * C_CH + c0);
        ushort4 u10 = *(const ushort4*)(fm + (size_t)(r0 + xc1) * C_CH + c0);
        ushort4 u01 = *(const ushort4*)(fm + (size_t)(r1 + xc0) * C_CH + c0);
        ushort4 u11 = *(const ushort4*)(fm + (size_t)(r1 + xc1) * C_CH + c0);

        float w00 = wx0 * wy0, w10 = wx1 * wy0;
        float w01 = wx0 * wy1, w11 = wx1 * wy1;

        acc.x = fmaf(bf2f(u00.x), w00, acc.x);
        acc.y = fmaf(bf2f(u00.y), w00, acc.y);
        acc.z = fmaf(bf2f(u00.z), w00, acc.z);
        acc.w = fmaf(bf2f(u00.w), w00, acc.w);
        acc.x = fmaf(bf2f(u10.x), w10, acc.x);
        acc.y = fmaf(bf2f(u10.y), w10, acc.y);
        acc.z = fmaf(bf2f(u10.z), w10, acc.z);
        acc.w = fmaf(bf2f(u10.w), w10, acc.w);
        acc.x = fmaf(bf2f(u01.x), w01, acc.x);
        acc.y = fmaf(bf2f(u01.y), w01, acc.y);
        acc.z = fmaf(bf2f(u01.z), w01, acc.z);
        acc.w = fmaf(bf2f(u01.w), w01, acc.w);
        acc.x = fmaf(bf2f(u11.x), w11, acc.x);
        acc.y = fmaf(bf2f(u11.y), w11, acc.y);
        acc.z = fmaf(bf2f(u11.z), w11, acc.z);
        acc.w = fmaf(bf2f(u11.w), w11, acc.w);
    }

    __shared__ float s_part[16][C_CH];
    __shared__ float s_tot[C_CH];
    __shared__ float s_proj[4][C_CH];

    *(float4*)&s_part[wv][c0] = acc;
    __syncthreads();

    if (tid < C_CH) {
        float t = 0.f;
#pragma unroll
        for (int i = 0; i < 16; ++i) t += s_part[i][tid];
        s_tot[tid] = t;
    }
    __syncthreads();

    {
        const int j = tid & (C_CH - 1);
        const int q = tid >> 8;
        const int kb = q * 64;
        float r0s = 0.f, r1s = 0.f, r2s = 0.f, r3s = 0.f;
#pragma unroll 4
        for (int k = kb; k < kb + 64; k += 4) {
            r0s = fmaf(s_tot[k + 0], wproj[(size_t)(k + 0) * C_CH + j], r0s);
            r1s = fmaf(s_tot[k + 1], wproj[(size_t)(k + 1) * C_CH + j], r1s);
            r2s = fmaf(s_tot[k + 2], wproj[(size_t)(k + 2) * C_CH + j], r2s);
            r3s = fmaf(s_tot[k + 3], wproj[(size_t)(k + 3) * C_CH + j], r3s);
        }
        s_proj[q][j] = (r0s + r1s) + (r2s + r3s);
    }
    __syncthreads();

    if (tid < C_CH) {
        float r = (s_proj[0][tid] + s_proj[1][tid]) + (s_proj[2][tid] + s_proj[3][tid])
                  + bproj[tid];
        out[(size_t)a * 512 + tid] = r;
    } else if (tid < 2 * C_CH) {
        const int j = tid - C_CH;
        out[(size_t)a * 512 + C_CH + j] = inst[(size_t)a * C_CH + j];
    }
}

// ---------------- fallback: fp32 gather (round-3 kernel) ----------------
__global__ __launch_bounds__(1024, 8) void daf_fused_fp32(
    const float* __restrict__ fm0, const float* __restrict__ fm1,
    const float* __restrict__ fm2, const float* __restrict__ fm3,
    const float* __restrict__ pts, const float* __restrict__ wts,
    const float* __restrict__ inst, const float* __restrict__ wproj,
    const float* __restrict__ bproj, float* __restrict__ out)
{
    const int a    = blockIdx.x;
    const int tid  = threadIdx.x;
    const int wv   = tid >> 6;
    const int lane = tid & 63;
    const int level = wv & 3;
    const int chunk = wv >> 2;

    const float* fm; int H, W;
    if (level == 0)      { fm = fm0; H = 64; W = 176; }
    else if (level == 1) { fm = fm1; H = 32; W = 88;  }
    else if (level == 2) { fm = fm2; H = 16; W = 44;  }
    else                 { fm = fm3; H = 8;  W = 22;  }
    const float fW = (float)W, fH = (float)H;
    const int HW = H * W;

    const int c0 = lane << 2;
    const int g  = lane >> 3;

    const float2* __restrict__ pts_a = (const float2*)(pts + (size_t)a * (N_PC * 2));
    const float*  __restrict__ wts_a = wts + (size_t)a * (N_PC * N_LVL * N_GRP);

    const int start = chunk * 20;
    const int end   = (chunk == 3) ? N_PC : (start + 20);

    float4 acc = make_float4(0.f, 0.f, 0.f, 0.f);

#pragma unroll 2
    for (int pc = start; pc < end; ++pc) {
        const int cam = pc % N_CAM;
        float2 pt = pts_a[pc];
        float x = pt.x * fW - 0.5f;
        float y = pt.y * fH - 0.5f;
        float x0f = floorf(x), y0f = floorf(y);
        int   x0 = (int)x0f,  y0 = (int)y0f;
        float wx1 = x - x0f,  wy1 = y - y0f;
        float wx0 = 1.f - wx1, wy0 = 1.f - wy1;
        if (x0 < 0 || x0 >= W)         wx0 = 0.f;
        if (x0 + 1 < 0 || x0 + 1 >= W) wx1 = 0.f;
        if (y0 < 0 || y0 >= H)         wy0 = 0.f;
        if (y0 + 1 < 0 || y0 + 1 >= H) wy1 = 0.f;

        float w = wts_a[pc * (N_LVL * N_GRP) + level * N_GRP + g];
        wx0 *= w; wx1 *= w;

        int xc0 = min(max(x0, 0), W - 1);
        int xc1 = min(max(x0 + 1, 0), W - 1);
        int yc0 = min(max(y0, 0), H - 1);
        int yc1 = min(max(y0 + 1, 0), H - 1);

        const int base = cam * HW;
        const int r0 = base + yc0 * W;
        const int r1 = base + yc1 * W;

        float4 v00 = *(const float4*)(fm + (size_t)(r0 + xc0) * C_CH + c0);
        float4 v10 = *(const float4*)(fm + (size_t)(r0 + xc1) * C_CH + c0);
        float4 v01 = *(const float4*)(fm + (size_t)(r1 + xc0) * C_CH + c0);
        float4 v11 = *(const float4*)(fm + (size_t)(r1 + xc1) * C_CH + c0);

        float w00 = wx0 * wy0, w10 = wx1 * wy0;
        float w01 = wx0 * wy1, w11 = wx1 * wy1;

        acc.x = fmaf(v00.x, w00, acc.x);
        acc.y = fmaf(v00.y, w00, acc.y);
        acc.z = fmaf(v00.z, w00, acc.z);
        acc.w = fmaf(v00.w, w00, acc.w);
        acc.x = fmaf(v10.x, w10, acc.x);
        acc.y = fmaf(v10.y, w10, acc.y);
        acc.z = fmaf(v10.z, w10, acc.z);
        acc.w = fmaf(v10.w, w10, acc.w);
        acc.x = fmaf(v01.x, w01, acc.x);
        acc.y = fmaf(v01.y, w01, acc.y);
        acc.z = fmaf(v01.z, w01, acc.z);
        acc.w = fmaf(v01.w, w01, acc.w);
        acc.x = fmaf(v11.x, w11, acc.x);
        acc.y = fmaf(v11.y, w11, acc.y);
        acc.z = fmaf(v11.z, w11, acc.z);
        acc.w = fmaf(v11.w, w11, acc.w);
    }

    __shared__ float s_part[16][C_CH];
    __shared__ float s_tot[C_CH];
    __shared__ float s_proj[4][C_CH];

    *(float4*)&s_part[wv][c0] = acc;
    __syncthreads();

    if (tid < C_CH) {
        float t = 0.f;
#pragma unroll
        for (int i = 0; i < 16; ++i) t += s_part[i][tid];
        s_tot[tid] = t;
    }
    __syncthreads();

    {
        const int j = tid & (C_CH - 1);
        const int q = tid >> 8;
        const int kb = q * 64;
        float r0s = 0.f, r1s = 0.f, r2s = 0.f, r3s = 0.f;
#pragma unroll 4
        for (int k = kb; k < kb + 64; k += 4) {
            r0s = fmaf(s_tot[k + 0], wproj[(size_t)(k + 0) * C_CH + j], r0s);
            r1s = fmaf(s_tot[k + 1], wproj[(size_t)(k + 1) * C_CH + j], r1s);
            r2s = fmaf(s_tot[k + 2], wproj[(size_t)(k + 2) * C_CH + j], r2s);
            r3s = fmaf(s_tot[k + 3], wproj[(size_t)(k + 3) * C_CH + j], r3s);
        }
        s_proj[q][j] = (r0s + r1s) + (r2s + r3s);
    }
    __syncthreads();

    if (tid < C_CH) {
        float r = (s_proj[0][tid] + s_proj[1][tid]) + (s_proj[2][tid] + s_proj[3][tid])
                  + bproj[tid];
        out[(size_t)a * 512 + tid] = r;
    } else if (tid < 2 * C_CH) {
        const int j = tid - C_CH;
        out[(size_t)a * 512 + C_CH + j] = inst[(size_t)a * C_CH + j];
    }
}

extern "C" void kernel_launch(void* const* d_in, const int* in_sizes, int n_in,
                              void* d_out, int out_size, void* d_ws, size_t ws_size,
                              hipStream_t stream) {
    const float* fm0   = (const float*)d_in[0];
    const float* fm1   = (const float*)d_in[1];
    const float* fm2   = (const float*)d_in[2];
    const float* fm3   = (const float*)d_in[3];
    const float* pts   = (const float*)d_in[4];
    const float* wts   = (const float*)d_in[5];
    const float* inst  = (const float*)d_in[6];
    const float* wproj = (const float*)d_in[7];
    const float* bproj = (const float*)d_in[8];
    float* out = (float*)d_out;

    if (ws_size >= WS_NEEDED) {
        unsigned short* fmw = (unsigned short*)d_ws;
        convert_bf16_kernel<<<2048, 256, 0, stream>>>(fm0, fm1, fm2, fm3, fmw);
        daf_fused_bf16<<<A_TOT, 1024, 0, stream>>>(
            fmw, pts, wts, inst, wproj, bproj, out);
    } else {
        daf_fused_fp32<<<A_TOT, 1024, 0, stream>>>(
            fm0, fm1, fm2, fm3, pts, wts, inst, wproj, bproj, out);
    }
}